// Round 8
// baseline (554.010 us; speedup 1.0000x reference)
//
#include <hip/hip_runtime.h>
#include <hip/hip_fp16.h>

static constexpr float kBnEps = 1e-5f;
static constexpr int MAXB = 1024;  // max dst-buckets (128 dsts each)

typedef __attribute__((ext_vector_type(8))) _Float16 f16x8;
typedef __attribute__((ext_vector_type(4))) float f32x4;

// ---------------------------------------------------------------------------
// Inline edge-format detection: int64 storage => all odd int32 words zero.
// Every wave computes the same answer from the first 64 odd words.
// ---------------------------------------------------------------------------
__device__ __forceinline__ int detect64(const int* __restrict__ eb) {
    int l = threadIdx.x & 63;
    int v = eb[2 * l + 1];
    unsigned long long m = __ballot(v == 0);
    return (m == ~0ull) ? 1 : 0;
}

__device__ __forceinline__ int edge_src(const int* eb, int is64, int E, int e) {
    return is64 ? eb[2 * e] : eb[e];
}
__device__ __forceinline__ int edge_dst(const int* eb, int is64, int E, int e) {
    return is64 ? eb[2 * E + 2 * e] : eb[E + e];
}

// ---------------------------------------------------------------------------
// prep_k: fused histA (dst-bucket histogram) + cvtx (x->fp16) + cvtw
// (weights->fp16). Block ranges: [0,HC) hist, [HC,HC+CX) cvtx, rest cvtw.
// ---------------------------------------------------------------------------
__global__ __launch_bounds__(256) void prep_k(
    const int* __restrict__ eb, int* __restrict__ gcnt, int E, int nbuck,
    const float* __restrict__ x, __half* __restrict__ x_h, int total8,
    const float* __restrict__ Wl0, const float* __restrict__ Wr0,
    const float* __restrict__ Wl1, const float* __restrict__ Wr1,
    const float* __restrict__ Wl2, const float* __restrict__ Wr2,
    const float* __restrict__ dW1, const float* __restrict__ dW3,
    const float* __restrict__ dW2, __half* __restrict__ Wcat,
    __half* __restrict__ dWcat, int HC, int CX) {
    __shared__ int lh[MAXB];
    int b = blockIdx.x;
    int tid = threadIdx.x;
    if (b < HC) {
        for (int i = tid; i < nbuck; i += 256) lh[i] = 0;
        __syncthreads();
        int is64 = detect64(eb);
        int base = b * 4096;
#pragma unroll
        for (int i = 0; i < 16; ++i) {
            int e = base + i * 256 + tid;
            if (e < E) {
                int d = edge_dst(eb, is64, E, e);
                atomicAdd(&lh[d >> 7], 1);
            }
        }
        __syncthreads();
        for (int i = tid; i < nbuck; i += 256) {
            int c = lh[i];
            if (c) atomicAdd(&gcnt[i], c);
        }
    } else if (b < HC + CX) {
        int i = (b - HC) * 256 + tid;
        if (i < total8) {
            float4 v0 = ((const float4*)x)[2 * i];
            float4 v1 = ((const float4*)x)[2 * i + 1];
            __half2 h0 = __floats2half2_rn(v0.x, v0.y);
            __half2 h1 = __floats2half2_rn(v0.z, v0.w);
            __half2 h2 = __floats2half2_rn(v1.x, v1.y);
            __half2 h3 = __floats2half2_rn(v1.z, v1.w);
            uint4 o;
            o.x = *(uint*)&h0; o.y = *(uint*)&h1; o.z = *(uint*)&h2; o.w = *(uint*)&h3;
            ((uint4*)x_h)[i] = o;
        }
    } else {
        int idx = (b - HC - CX) * 256 + tid;
        if (idx < 3 * 32768) {
            int l = idx >> 15;
            int rem = idx & 32767;
            int nn = rem >> 8;
            int k = rem & 255;
            const float* Wl = (l == 0) ? Wl0 : (l == 1) ? Wl1 : Wl2;
            const float* Wr = (l == 0) ? Wr0 : (l == 1) ? Wr1 : Wr2;
            float v = (k < 128) ? Wl[nn * 128 + k] : Wr[nn * 128 + (k - 128)];
            Wcat[idx] = __float2half_rn(v);
        } else if (idx < 3 * 32768 + 3 * 16384) {
            int j = idx - 3 * 32768;
            int blk = j >> 14;
            int r = (j & 16383) >> 7;
            int c = j & 127;
            float v;
            if (blk == 0) v = dW1[r * 128 + c];
            else if (blk == 1) v = dW3[r * 128 + c];
            else v = (r < 7) ? dW2[r * 128 + c] : 0.f;
            dWcat[j] = __float2half_rn(v);
        }
    }
}

// ---------------------------------------------------------------------------
// scanB: bucket bases + cursors
// ---------------------------------------------------------------------------
__global__ __launch_bounds__(512) void scanB_k(const int* __restrict__ gcnt,
                                               int* __restrict__ gbase,
                                               int* __restrict__ gcur,
                                               int* __restrict__ offs, int E,
                                               int n, int nbuck) {
    __shared__ int s[512];
    int tid = threadIdx.x;
    int v = (tid < nbuck) ? gcnt[tid] : 0;
    s[tid] = v;
    __syncthreads();
    for (int d = 1; d < 512; d <<= 1) {
        int t = (tid >= d) ? s[tid - d] : 0;
        __syncthreads();
        s[tid] += t;
        __syncthreads();
    }
    if (tid < nbuck) {
        gbase[tid] = s[tid] - v;
        gcur[tid] = s[tid] - v;
    }
    if (tid == 0) {
        gbase[nbuck] = E;
        offs[n] = E;
    }
}

// ---------------------------------------------------------------------------
// binC: pack edges into bucket regions as (src<<7 | dst&127)
// ---------------------------------------------------------------------------
__global__ __launch_bounds__(256) void binC_k(const int* __restrict__ eb,
                                              int* __restrict__ gcur,
                                              unsigned* __restrict__ bins, int E,
                                              int nbuck) {
    __shared__ int lh[MAXB];
    __shared__ int lcur[MAXB];
    for (int i = threadIdx.x; i < nbuck; i += 256) lh[i] = 0;
    __syncthreads();
    int is64 = detect64(eb);
    int base = blockIdx.x * 4096;
    int ds[16], ss[16];
#pragma unroll
    for (int i = 0; i < 16; ++i) {
        int e = base + i * 256 + threadIdx.x;
        ds[i] = -1;
        if (e < E) {
            ds[i] = edge_dst(eb, is64, E, e);
            ss[i] = edge_src(eb, is64, E, e);
            atomicAdd(&lh[ds[i] >> 7], 1);
        }
    }
    __syncthreads();
    for (int b = threadIdx.x; b < nbuck; b += 256) {
        int c = lh[b];
        lcur[b] = c ? atomicAdd(&gcur[b], c) : 0;
    }
    __syncthreads();
#pragma unroll
    for (int i = 0; i < 16; ++i) {
        if (ds[i] >= 0) {
            int bkt = ds[i] >> 7;
            int p = atomicAdd(&lcur[bkt], 1);
            bins[p] = ((unsigned)ss[i] << 7) | (unsigned)(ds[i] & 127);
        }
    }
}

// ---------------------------------------------------------------------------
// csrD: per-bucket offs[] + csr[]; also accumulate degree histogram (for
// the degree-sorted node permutation).
// ---------------------------------------------------------------------------
__global__ __launch_bounds__(256) void csrD_k(const unsigned* __restrict__ bins,
                                              const int* __restrict__ gbase,
                                              int* __restrict__ offs,
                                              int* __restrict__ csr,
                                              int* __restrict__ dbin, int n) {
    int b = blockIdx.x;
    __shared__ int hist[128];
    __shared__ int s[128];
    __shared__ int cur[128];
    int tid = threadIdx.x;
    if (tid < 128) hist[tid] = 0;
    __syncthreads();
    int base = gbase[b], endb = gbase[b + 1], m = endb - base;
    for (int i = tid; i < m; i += 256) atomicAdd(&hist[bins[base + i] & 127u], 1);
    __syncthreads();
    int v = 0;
    if (tid < 128) {
        v = hist[tid];
        s[tid] = v;
    }
    __syncthreads();
    for (int d = 1; d < 128; d <<= 1) {
        int t = (tid >= d && tid < 128) ? s[tid - d] : 0;
        __syncthreads();
        if (tid < 128) s[tid] += t;
        __syncthreads();
    }
    if (tid < 128) {
        int excl = s[tid] - v;
        int dst = b * 128 + tid;
        if (dst < n) {
            offs[dst] = base + excl;
            atomicAdd(&dbin[v > 255 ? 255 : v], 1);  // degree histogram
        }
        cur[tid] = base + excl;
    }
    __syncthreads();
    for (int i = tid; i < m; i += 256) {
        unsigned u = bins[base + i];
        int p = atomicAdd(&cur[u & 127u], 1);
        csr[p] = (int)(u >> 7);
    }
}

// ---------------------------------------------------------------------------
// dscan: exclusive scan of the 256 degree bins -> cursors
// ---------------------------------------------------------------------------
__global__ __launch_bounds__(256) void dscan_k(const int* __restrict__ dbin,
                                               int* __restrict__ dcur) {
    __shared__ int s[256];
    int tid = threadIdx.x;
    int v = dbin[tid];
    s[tid] = v;
    __syncthreads();
    for (int d = 1; d < 256; d <<= 1) {
        int t = (tid >= d) ? s[tid - d] : 0;
        __syncthreads();
        s[tid] += t;
        __syncthreads();
    }
    dcur[tid] = s[tid] - v;
}

// ---------------------------------------------------------------------------
// dscat: counting-sort scatter of node ids by degree -> perm
// ---------------------------------------------------------------------------
__global__ __launch_bounds__(256) void dscat_k(const int* __restrict__ offs,
                                               int* __restrict__ dcur,
                                               int* __restrict__ perm, int n) {
    int i = blockIdx.x * 256 + threadIdx.x;
    if (i >= n) return;
    int deg = offs[i + 1] - offs[i];
    int b = deg > 255 ? 255 : deg;
    int pos = atomicAdd(&dcur[b], 1);
    perm[pos] = i;
}

// ---------------------------------------------------------------------------
// agg4: mean aggregation, k-quartered + XCD-pinned.
// Quarter q = (blockIdx&7)>>1 (empirical blockIdx%8 -> XCD mapping: each
// quarter's 3.2MB working set stays in 2 XCDs' L2s). Wave = 4 nodes x 16
// lanes; nodes taken from the degree-sorted perm so the 4 have ~equal len.
// 8-deep batched 64B row-quarter loads per group. fp32 acc, fp16 store.
// ---------------------------------------------------------------------------
__global__ __launch_bounds__(256) void agg4_k(const __half* __restrict__ Xh,
                                              const int* __restrict__ offs,
                                              const int* __restrict__ csr,
                                              const int* __restrict__ perm,
                                              __half* __restrict__ aggh, int n,
                                              int G) {
    int bid = blockIdx.x;
    int q = (bid & 7) >> 1;                // k-quarter 0..3
    int gi = (bid >> 3) * 2 + (bid & 1);   // node-group (16 nodes)
    if (gi >= G) return;
    int wv = threadIdx.x >> 6;
    int lane = threadIdx.x & 63;
    int grp = lane >> 4, lg = lane & 15;
    int slot = gi * 16 + wv * 4 + grp;
    int node = (slot < n) ? perm[slot] : -1;
    int beg = 0, len = 0;
    if (node >= 0) {
        beg = offs[node];
        len = offs[node + 1] - beg;
    }
    int lm1 = len - 1;
    const uint* Xp = (const uint*)Xh;
    float a0 = 0.f, a1 = 0.f;
    for (int j0 = 0; j0 < len; j0 += 8) {
        int idx[8];
#pragma unroll
        for (int t = 0; t < 8; ++t) {
            int jj = j0 + t;
            idx[t] = csr[beg + (jj < lm1 ? jj : lm1)];
        }
        uint v[8];
#pragma unroll
        for (int t = 0; t < 8; ++t)
            v[t] = Xp[(size_t)idx[t] * 64 + q * 16 + lg];
#pragma unroll
        for (int t = 0; t < 8; ++t) {
            if (j0 + t < len) {
                __half2 h = *(__half2*)&v[t];
                a0 += __low2float(h);
                a1 += __high2float(h);
            }
        }
    }
    if (node >= 0) {
        float inv = 1.0f / fmaxf((float)len, 1.0f);
        __half2 o = __floats2half2_rn(a0 * inv, a1 * inv);
        ((uint*)aggh)[(size_t)node * 64 + q * 16 + lg] = *(uint*)&o;
    }
}

// ---------------------------------------------------------------------------
// MFMA GEMM.
//   Layer mode: out = epi( [A0|A1] @ Bw.T ), KTOT=256, TWO_SRC.
//   Heads mode (HEADS=true, KTOT=128): gridDim.y=3 ->
//     y=0: out0[n][128] = A0 @ dW1.T + db1
//     y=1: out2[n][128] = A0 @ dW3.T + db3
//     y=2: out1[n][7]   = A0 @ dW2.T + db2 (zero-padded weight block)
// ---------------------------------------------------------------------------
template <int KTOT, bool TWO_SRC, bool BN_RELU, bool OUT16, bool HEADS>
__global__ __launch_bounds__(256) void mgemm_k(
    const __half* __restrict__ A0, const __half* __restrict__ A1,
    const __half* __restrict__ Bw, const float* __restrict__ bias,
    const float* __restrict__ g, const float* __restrict__ be,
    void* __restrict__ outv, const float* __restrict__ bias2,
    void* __restrict__ outv2, const float* __restrict__ bias3,
    void* __restrict__ outv3, int n) {
    constexpr int ROWB = KTOT * 2 + 16;  // padded row bytes: 2-way banks = free
    __shared__ char sA[128 * ROWB];

    int ncol = 128, ostride = 128;
    if (HEADS) {
        int y = blockIdx.y;
        Bw += (size_t)y * 128 * KTOT;
        if (y == 1) { bias = bias2; outv = outv2; }
        if (y == 2) { bias = bias3; outv = outv3; ncol = 7; ostride = 7; }
    }

    const int tid = threadIdx.x;
    const int lane = tid & 63;
    const int wid = tid >> 6;
    const int wm = wid & 1;
    const int wn = wid >> 1;
    const int row0 = blockIdx.x * 128;

    constexpr int CPR = KTOT / 8;  // 16B chunks per row
#pragma unroll
    for (int i = 0; i < (128 * CPR) / 256; ++i) {
        int idx = tid + i * 256;
        int r = idx / CPR;
        int c = idx % CPR;
        int rg = row0 + r;
        float4 v = make_float4(0.f, 0.f, 0.f, 0.f);
        if (rg < n) {
            if (TWO_SRC)
                v = (c < 16) ? *(const float4*)(A0 + (size_t)rg * 128 + c * 8)
                             : *(const float4*)(A1 + (size_t)rg * 128 + (c - 16) * 8);
            else
                v = *(const float4*)(A0 + (size_t)rg * 128 + c * 8);
        }
        *(float4*)(&sA[r * ROWB + c * 16]) = v;
    }

    f32x4 acc[4][4];
#pragma unroll
    for (int mi = 0; mi < 4; ++mi)
#pragma unroll
        for (int ni = 0; ni < 4; ++ni) acc[mi][ni] = (f32x4){0.f, 0.f, 0.f, 0.f};

    __syncthreads();

    const int bcol = wn * 64;
    constexpr int KH = KTOT / 128;
#pragma unroll
    for (int kh = 0; kh < KH; ++kh) {
        f16x8 bfr[4][4];
#pragma unroll
        for (int ni = 0; ni < 4; ++ni)
#pragma unroll
            for (int kt = 0; kt < 4; ++kt) {
                int col = bcol + ni * 16 + (lane & 15);
                int ko = kh * 128 + kt * 32 + (lane >> 4) * 8;
                bfr[ni][kt] = *(const f16x8*)(Bw + (size_t)col * KTOT + ko);
            }
#pragma unroll
        for (int mi = 0; mi < 4; ++mi) {
            int rl = wm * 64 + mi * 16 + (lane & 15);
            const char* base = &sA[rl * ROWB + kh * 256 + (lane >> 4) * 16];
            f16x8 afr[4];
#pragma unroll
            for (int kt = 0; kt < 4; ++kt) afr[kt] = *(const f16x8*)(base + kt * 64);
#pragma unroll
            for (int kt = 0; kt < 4; ++kt)
#pragma unroll
                for (int ni = 0; ni < 4; ++ni)
                    acc[mi][ni] = __builtin_amdgcn_mfma_f32_16x16x32_f16(
                        afr[kt], bfr[ni][kt], acc[mi][ni], 0, 0, 0);
        }
    }

#pragma unroll
    for (int ni = 0; ni < 4; ++ni) {
        int col = bcol + ni * 16 + (lane & 15);
        if (HEADS && col >= ncol) continue;
        float bv = bias[col];
        float gs = 0.f, bes = 0.f;
        if (BN_RELU) {
            gs = g[col] / sqrtf(1.0f + kBnEps);
            bes = be[col];
        }
#pragma unroll
        for (int mi = 0; mi < 4; ++mi) {
#pragma unroll
            for (int r = 0; r < 4; ++r) {
                int row = row0 + wm * 64 + mi * 16 + (lane >> 4) * 4 + r;
                if (row < n) {
                    float v = acc[mi][ni][r] + bv;
                    if (BN_RELU) v = fmaxf(v * gs + bes, 0.f);
                    if (OUT16)
                        ((__half*)outv)[(size_t)row * 128 + col] = __float2half_rn(v);
                    else
                        ((float*)outv)[(size_t)row * ostride + col] = v;
                }
            }
        }
    }
}

// ---------------------------------------------------------------------------
extern "C" void kernel_launch(void* const* d_in, const int* in_sizes, int n_in,
                              void* d_out, int out_size, void* d_ws, size_t ws_size,
                              hipStream_t stream) {
    const float* x   = (const float*)d_in[0];
    const int*   eb  = (const int*)d_in[1];
    const float* Wl0 = (const float*)d_in[2];
    const float* Wr0 = (const float*)d_in[3];
    const float* b0  = (const float*)d_in[4];
    const float* Wl1 = (const float*)d_in[5];
    const float* Wr1 = (const float*)d_in[6];
    const float* b1  = (const float*)d_in[7];
    const float* Wl2 = (const float*)d_in[8];
    const float* Wr2 = (const float*)d_in[9];
    const float* b2  = (const float*)d_in[10];
    const float* g0  = (const float*)d_in[11];
    const float* be0 = (const float*)d_in[12];
    const float* g1  = (const float*)d_in[13];
    const float* be1 = (const float*)d_in[14];
    const float* dW1 = (const float*)d_in[15];
    const float* db1 = (const float*)d_in[16];
    const float* dW2 = (const float*)d_in[17];
    const float* db2 = (const float*)d_in[18];
    const float* dW3 = (const float*)d_in[19];
    const float* db3 = (const float*)d_in[20];

    const int n = in_sizes[0] / 128;
    const int E = in_sizes[1] / 2;
    const int nbuck = (n + 127) >> 7;

    char* ws = (char*)d_ws;
    size_t off = 0;
    auto alloc = [&](size_t bytes) -> void* {
        void* p = ws + off;
        off = (off + bytes + 255) & ~(size_t)255;
        return p;
    };
    int*      gcnt  = (int*)alloc(MAXB * 4);      // 4096B, 256-aligned
    int*      dbin  = (int*)alloc(256 * 4);       // contiguous after gcnt
    int*      dcur  = (int*)alloc(256 * 4);
    int*      gbase = (int*)alloc((MAXB + 1) * 4);
    int*      gcur  = (int*)alloc(MAXB * 4);
    unsigned* bins  = (unsigned*)alloc((size_t)E * 4);
    int*      csr   = (int*)alloc((size_t)E * 4);
    int*      offs  = (int*)alloc((size_t)(n + 1) * 4);
    int*      perm  = (int*)alloc((size_t)n * 4);
    __half*   x_h   = (__half*)alloc((size_t)n * 128 * 2);
    __half*   agg_h = (__half*)alloc((size_t)n * 128 * 2);
    __half*   h0    = (__half*)alloc((size_t)n * 128 * 2);
    __half*   h1    = (__half*)alloc((size_t)n * 128 * 2);
    __half*   h2    = h0;  // h0 dead after layer-1 gemm
    __half*   Wcat  = (__half*)alloc(3 * 32768 * 2);
    __half*   dWcat = (__half*)alloc(3 * 16384 * 2);

    float* out0 = (float*)d_out;
    float* out1 = out0 + (size_t)n * 128;
    float* out2 = out1 + (size_t)n * 7;

    // zero gcnt + dbin (contiguous)
    hipMemsetAsync(gcnt, 0, MAXB * 4 + 256 * 4, stream);

    const int ggrid = (n + 127) / 128;
    const int HC = (E + 4095) / 4096;
    const int CX = (n * 16 + 255) / 256;
    const int CW = (147456 + 255) / 256;
    const int G = (n + 15) / 16;
    const int agg_grid = ((G + 1) / 2) * 8;

    prep_k<<<HC + CX + CW, 256, 0, stream>>>(eb, gcnt, E, nbuck, x, x_h, n * 16,
                                             Wl0, Wr0, Wl1, Wr1, Wl2, Wr2, dW1,
                                             dW3, dW2, Wcat, dWcat, HC, CX);
    scanB_k<<<1, 512, 0, stream>>>(gcnt, gbase, gcur, offs, E, n, nbuck);
    binC_k<<<HC, 256, 0, stream>>>(eb, gcur, bins, E, nbuck);
    csrD_k<<<nbuck, 256, 0, stream>>>(bins, gbase, offs, csr, dbin, n);
    dscan_k<<<1, 256, 0, stream>>>(dbin, dcur);
    dscat_k<<<(n + 255) / 256, 256, 0, stream>>>(offs, dcur, perm, n);

    // layer 0
    agg4_k<<<agg_grid, 256, 0, stream>>>(x_h, offs, csr, perm, agg_h, n, G);
    mgemm_k<256, true, true, true, false><<<ggrid, 256, 0, stream>>>(
        agg_h, x_h, Wcat, b0, g0, be0, h0, nullptr, nullptr, nullptr, nullptr, n);
    // layer 1
    agg4_k<<<agg_grid, 256, 0, stream>>>(h0, offs, csr, perm, agg_h, n, G);
    mgemm_k<256, true, true, true, false><<<ggrid, 256, 0, stream>>>(
        agg_h, h0, Wcat + 32768, b1, g1, be1, h1, nullptr, nullptr, nullptr,
        nullptr, n);
    // layer 2 (no bn/relu); h2 aliases h0
    agg4_k<<<agg_grid, 256, 0, stream>>>(h1, offs, csr, perm, agg_h, n, G);
    mgemm_k<256, true, false, true, false><<<ggrid, 256, 0, stream>>>(
        agg_h, h1, Wcat + 65536, b2, nullptr, nullptr, h2, nullptr, nullptr,
        nullptr, nullptr, n);
    // fused heads: y=0 -> dW1/db1 -> out0; y=1 -> dW3/db3 -> out2;
    //              y=2 -> dW2(pad)/db2 -> out1 (7 cols)
    mgemm_k<128, false, false, false, true><<<dim3(ggrid, 3), 256, 0, stream>>>(
        h2, nullptr, dWcat, db1, nullptr, nullptr, out0, db3, out2, db2,
        out1, n);
}

// Round 9
// 239.588 us; speedup vs baseline: 2.3124x; 2.3124x over previous
//
#include <hip/hip_runtime.h>
#include <hip/hip_fp16.h>

static constexpr float kBnEps = 1e-5f;
static constexpr int MAXB = 1024;  // max dst-buckets (128 dsts each)

typedef __attribute__((ext_vector_type(8))) _Float16 f16x8;
typedef __attribute__((ext_vector_type(4))) float f32x4;

// ---------------------------------------------------------------------------
// Inline edge-format detection: int64 storage => all odd int32 words zero.
// ---------------------------------------------------------------------------
__device__ __forceinline__ int detect64(const int* __restrict__ eb) {
    int l = threadIdx.x & 63;
    int v = eb[2 * l + 1];
    unsigned long long m = __ballot(v == 0);
    return (m == ~0ull) ? 1 : 0;
}

__device__ __forceinline__ int edge_src(const int* eb, int is64, int E, int e) {
    return is64 ? eb[2 * e] : eb[e];
}
__device__ __forceinline__ int edge_dst(const int* eb, int is64, int E, int e) {
    return is64 ? eb[2 * E + 2 * e] : eb[E + e];
}

// ---------------------------------------------------------------------------
// prep_k: fused histA (dst-bucket histogram) + cvtx (x->fp16) + cvtw
// (weights->fp16). Block ranges: [0,HC) hist, [HC,HC+CX) cvtx, rest cvtw.
// ---------------------------------------------------------------------------
__global__ __launch_bounds__(256) void prep_k(
    const int* __restrict__ eb, int* __restrict__ gcnt, int E, int nbuck,
    const float* __restrict__ x, __half* __restrict__ x_h, int total8,
    const float* __restrict__ Wl0, const float* __restrict__ Wr0,
    const float* __restrict__ Wl1, const float* __restrict__ Wr1,
    const float* __restrict__ Wl2, const float* __restrict__ Wr2,
    const float* __restrict__ dW1, const float* __restrict__ dW3,
    const float* __restrict__ dW2, __half* __restrict__ Wcat,
    __half* __restrict__ dWcat, int HC, int CX) {
    __shared__ int lh[MAXB];
    int b = blockIdx.x;
    int tid = threadIdx.x;
    if (b < HC) {
        for (int i = tid; i < nbuck; i += 256) lh[i] = 0;
        __syncthreads();
        int is64 = detect64(eb);
        int base = b * 4096;
#pragma unroll
        for (int i = 0; i < 16; ++i) {
            int e = base + i * 256 + tid;
            if (e < E) {
                int d = edge_dst(eb, is64, E, e);
                atomicAdd(&lh[d >> 7], 1);
            }
        }
        __syncthreads();
        for (int i = tid; i < nbuck; i += 256) {
            int c = lh[i];
            if (c) atomicAdd(&gcnt[i], c);
        }
    } else if (b < HC + CX) {
        int i = (b - HC) * 256 + tid;
        if (i < total8) {
            float4 v0 = ((const float4*)x)[2 * i];
            float4 v1 = ((const float4*)x)[2 * i + 1];
            __half2 h0 = __floats2half2_rn(v0.x, v0.y);
            __half2 h1 = __floats2half2_rn(v0.z, v0.w);
            __half2 h2 = __floats2half2_rn(v1.x, v1.y);
            __half2 h3 = __floats2half2_rn(v1.z, v1.w);
            uint4 o;
            o.x = *(uint*)&h0; o.y = *(uint*)&h1; o.z = *(uint*)&h2; o.w = *(uint*)&h3;
            ((uint4*)x_h)[i] = o;
        }
    } else {
        int idx = (b - HC - CX) * 256 + tid;
        if (idx < 3 * 32768) {
            int l = idx >> 15;
            int rem = idx & 32767;
            int nn = rem >> 8;
            int k = rem & 255;
            const float* Wl = (l == 0) ? Wl0 : (l == 1) ? Wl1 : Wl2;
            const float* Wr = (l == 0) ? Wr0 : (l == 1) ? Wr1 : Wr2;
            float v = (k < 128) ? Wl[nn * 128 + k] : Wr[nn * 128 + (k - 128)];
            Wcat[idx] = __float2half_rn(v);
        } else if (idx < 3 * 32768 + 3 * 16384) {
            int j = idx - 3 * 32768;
            int blk = j >> 14;
            int r = (j & 16383) >> 7;
            int c = j & 127;
            float v;
            if (blk == 0) v = dW1[r * 128 + c];
            else if (blk == 1) v = dW3[r * 128 + c];
            else v = (r < 7) ? dW2[r * 128 + c] : 0.f;
            dWcat[j] = __float2half_rn(v);
        }
    }
}

// ---------------------------------------------------------------------------
// scanB: bucket bases + cursors
// ---------------------------------------------------------------------------
__global__ __launch_bounds__(512) void scanB_k(const int* __restrict__ gcnt,
                                               int* __restrict__ gbase,
                                               int* __restrict__ gcur,
                                               int* __restrict__ offs, int E,
                                               int n, int nbuck) {
    __shared__ int s[512];
    int tid = threadIdx.x;
    int v = (tid < nbuck) ? gcnt[tid] : 0;
    s[tid] = v;
    __syncthreads();
    for (int d = 1; d < 512; d <<= 1) {
        int t = (tid >= d) ? s[tid - d] : 0;
        __syncthreads();
        s[tid] += t;
        __syncthreads();
    }
    if (tid < nbuck) {
        gbase[tid] = s[tid] - v;
        gcur[tid] = s[tid] - v;
    }
    if (tid == 0) {
        gbase[nbuck] = E;
        offs[n] = E;
    }
}

// ---------------------------------------------------------------------------
// binC: pack edges into bucket regions as (src<<7 | dst&127)
// ---------------------------------------------------------------------------
__global__ __launch_bounds__(256) void binC_k(const int* __restrict__ eb,
                                              int* __restrict__ gcur,
                                              unsigned* __restrict__ bins, int E,
                                              int nbuck) {
    __shared__ int lh[MAXB];
    __shared__ int lcur[MAXB];
    for (int i = threadIdx.x; i < nbuck; i += 256) lh[i] = 0;
    __syncthreads();
    int is64 = detect64(eb);
    int base = blockIdx.x * 4096;
    int ds[16], ss[16];
#pragma unroll
    for (int i = 0; i < 16; ++i) {
        int e = base + i * 256 + threadIdx.x;
        ds[i] = -1;
        if (e < E) {
            ds[i] = edge_dst(eb, is64, E, e);
            ss[i] = edge_src(eb, is64, E, e);
            atomicAdd(&lh[ds[i] >> 7], 1);
        }
    }
    __syncthreads();
    for (int b = threadIdx.x; b < nbuck; b += 256) {
        int c = lh[b];
        lcur[b] = c ? atomicAdd(&gcur[b], c) : 0;
    }
    __syncthreads();
#pragma unroll
    for (int i = 0; i < 16; ++i) {
        if (ds[i] >= 0) {
            int bkt = ds[i] >> 7;
            int p = atomicAdd(&lcur[bkt], 1);
            bins[p] = ((unsigned)ss[i] << 7) | (unsigned)(ds[i] & 127);
        }
    }
}

// ---------------------------------------------------------------------------
// csrD: per-bucket offs[] + csr[] (r4 form — no degree histogram)
// ---------------------------------------------------------------------------
__global__ __launch_bounds__(256) void csrD_k(const unsigned* __restrict__ bins,
                                              const int* __restrict__ gbase,
                                              int* __restrict__ offs,
                                              int* __restrict__ csr, int n) {
    int b = blockIdx.x;
    __shared__ int hist[128];
    __shared__ int s[128];
    __shared__ int cur[128];
    int tid = threadIdx.x;
    if (tid < 128) hist[tid] = 0;
    __syncthreads();
    int base = gbase[b], endb = gbase[b + 1], m = endb - base;
    for (int i = tid; i < m; i += 256) atomicAdd(&hist[bins[base + i] & 127u], 1);
    __syncthreads();
    int v = 0;
    if (tid < 128) {
        v = hist[tid];
        s[tid] = v;
    }
    __syncthreads();
    for (int d = 1; d < 128; d <<= 1) {
        int t = (tid >= d && tid < 128) ? s[tid - d] : 0;
        __syncthreads();
        if (tid < 128) s[tid] += t;
        __syncthreads();
    }
    if (tid < 128) {
        int excl = s[tid] - v;
        int dst = b * 128 + tid;
        if (dst < n) offs[dst] = base + excl;
        cur[tid] = base + excl;
    }
    __syncthreads();
    for (int i = tid; i < m; i += 256) {
        unsigned u = bins[base + i];
        int p = atomicAdd(&cur[u & 127u], 1);
        csr[p] = (int)(u >> 7);
    }
}

// ---------------------------------------------------------------------------
// Mean aggregation (round-4-proven): one wave per node, lane owns dword
// (2 cols) of the 128-col fp16 row, 8-deep independent row loads in flight.
// fp32 accumulate, fp16 store.
// ---------------------------------------------------------------------------
__global__ void agg_k(const __half* __restrict__ Xh, const int* __restrict__ offs,
                      const int* __restrict__ csr, __half* __restrict__ aggh, int n) {
    int gt = blockIdx.x * blockDim.x + threadIdx.x;
    int wid = gt >> 6;
    int lane = threadIdx.x & 63;
    if (wid >= n) return;
    int beg = offs[wid], end = offs[wid + 1];
    int len = end - beg;
    const uint* Xp = (const uint*)Xh;
    float a0 = 0.f, a1 = 0.f;
    for (int j0 = 0; j0 < len; j0 += 8) {
        int idx[8];
        float w[8];
#pragma unroll
        for (int t = 0; t < 8; ++t) {
            int jj = j0 + t;
            bool ok = jj < len;
            idx[t] = csr[beg + (ok ? jj : 0)];
            w[t] = ok ? 1.f : 0.f;
        }
        uint v[8];
#pragma unroll
        for (int t = 0; t < 8; ++t)
            v[t] = Xp[(size_t)idx[t] * 64 + lane];
#pragma unroll
        for (int t = 0; t < 8; ++t) {
            __half2 h = *(__half2*)&v[t];
            a0 += w[t] * __low2float(h);
            a1 += w[t] * __high2float(h);
        }
    }
    float inv = 1.0f / fmaxf((float)len, 1.0f);
    __half2 o = __floats2half2_rn(a0 * inv, a1 * inv);
    ((uint*)aggh)[(size_t)wid * 64 + lane] = *(uint*)&o;
}

// ---------------------------------------------------------------------------
// MFMA GEMM.
//   Layer mode: out = epi( [A0|A1] @ Bw.T ), KTOT=256, TWO_SRC.
//   Heads mode (HEADS=true, KTOT=128): gridDim.y=3 ->
//     y=0: out0[n][128] = A0 @ dW1.T + db1
//     y=1: out2[n][128] = A0 @ dW3.T + db3
//     y=2: out1[n][7]   = A0 @ dW2.T + db2 (zero-padded weight block)
// ---------------------------------------------------------------------------
template <int KTOT, bool TWO_SRC, bool BN_RELU, bool OUT16, bool HEADS>
__global__ __launch_bounds__(256) void mgemm_k(
    const __half* __restrict__ A0, const __half* __restrict__ A1,
    const __half* __restrict__ Bw, const float* __restrict__ bias,
    const float* __restrict__ g, const float* __restrict__ be,
    void* __restrict__ outv, const float* __restrict__ bias2,
    void* __restrict__ outv2, const float* __restrict__ bias3,
    void* __restrict__ outv3, int n) {
    constexpr int ROWB = KTOT * 2 + 16;  // padded row bytes: 2-way banks = free
    __shared__ char sA[128 * ROWB];

    int ncol = 128, ostride = 128;
    if (HEADS) {
        int y = blockIdx.y;
        Bw += (size_t)y * 128 * KTOT;
        if (y == 1) { bias = bias2; outv = outv2; }
        if (y == 2) { bias = bias3; outv = outv3; ncol = 7; ostride = 7; }
    }

    const int tid = threadIdx.x;
    const int lane = tid & 63;
    const int wid = tid >> 6;
    const int wm = wid & 1;
    const int wn = wid >> 1;
    const int row0 = blockIdx.x * 128;

    constexpr int CPR = KTOT / 8;  // 16B chunks per row
#pragma unroll
    for (int i = 0; i < (128 * CPR) / 256; ++i) {
        int idx = tid + i * 256;
        int r = idx / CPR;
        int c = idx % CPR;
        int rg = row0 + r;
        float4 v = make_float4(0.f, 0.f, 0.f, 0.f);
        if (rg < n) {
            if (TWO_SRC)
                v = (c < 16) ? *(const float4*)(A0 + (size_t)rg * 128 + c * 8)
                             : *(const float4*)(A1 + (size_t)rg * 128 + (c - 16) * 8);
            else
                v = *(const float4*)(A0 + (size_t)rg * 128 + c * 8);
        }
        *(float4*)(&sA[r * ROWB + c * 16]) = v;
    }

    f32x4 acc[4][4];
#pragma unroll
    for (int mi = 0; mi < 4; ++mi)
#pragma unroll
        for (int ni = 0; ni < 4; ++ni) acc[mi][ni] = (f32x4){0.f, 0.f, 0.f, 0.f};

    __syncthreads();

    const int bcol = wn * 64;
    constexpr int KH = KTOT / 128;
#pragma unroll
    for (int kh = 0; kh < KH; ++kh) {
        f16x8 bfr[4][4];
#pragma unroll
        for (int ni = 0; ni < 4; ++ni)
#pragma unroll
            for (int kt = 0; kt < 4; ++kt) {
                int col = bcol + ni * 16 + (lane & 15);
                int ko = kh * 128 + kt * 32 + (lane >> 4) * 8;
                bfr[ni][kt] = *(const f16x8*)(Bw + (size_t)col * KTOT + ko);
            }
#pragma unroll
        for (int mi = 0; mi < 4; ++mi) {
            int rl = wm * 64 + mi * 16 + (lane & 15);
            const char* base = &sA[rl * ROWB + kh * 256 + (lane >> 4) * 16];
            f16x8 afr[4];
#pragma unroll
            for (int kt = 0; kt < 4; ++kt) afr[kt] = *(const f16x8*)(base + kt * 64);
#pragma unroll
            for (int kt = 0; kt < 4; ++kt)
#pragma unroll
                for (int ni = 0; ni < 4; ++ni)
                    acc[mi][ni] = __builtin_amdgcn_mfma_f32_16x16x32_f16(
                        afr[kt], bfr[ni][kt], acc[mi][ni], 0, 0, 0);
        }
    }

#pragma unroll
    for (int ni = 0; ni < 4; ++ni) {
        int col = bcol + ni * 16 + (lane & 15);
        if (HEADS && col >= ncol) continue;
        float bv = bias[col];
        float gs = 0.f, bes = 0.f;
        if (BN_RELU) {
            gs = g[col] / sqrtf(1.0f + kBnEps);
            bes = be[col];
        }
#pragma unroll
        for (int mi = 0; mi < 4; ++mi) {
#pragma unroll
            for (int r = 0; r < 4; ++r) {
                int row = row0 + wm * 64 + mi * 16 + (lane >> 4) * 4 + r;
                if (row < n) {
                    float v = acc[mi][ni][r] + bv;
                    if (BN_RELU) v = fmaxf(v * gs + bes, 0.f);
                    if (OUT16)
                        ((__half*)outv)[(size_t)row * 128 + col] = __float2half_rn(v);
                    else
                        ((float*)outv)[(size_t)row * ostride + col] = v;
                }
            }
        }
    }
}

// ---------------------------------------------------------------------------
extern "C" void kernel_launch(void* const* d_in, const int* in_sizes, int n_in,
                              void* d_out, int out_size, void* d_ws, size_t ws_size,
                              hipStream_t stream) {
    const float* x   = (const float*)d_in[0];
    const int*   eb  = (const int*)d_in[1];
    const float* Wl0 = (const float*)d_in[2];
    const float* Wr0 = (const float*)d_in[3];
    const float* b0  = (const float*)d_in[4];
    const float* Wl1 = (const float*)d_in[5];
    const float* Wr1 = (const float*)d_in[6];
    const float* b1  = (const float*)d_in[7];
    const float* Wl2 = (const float*)d_in[8];
    const float* Wr2 = (const float*)d_in[9];
    const float* b2  = (const float*)d_in[10];
    const float* g0  = (const float*)d_in[11];
    const float* be0 = (const float*)d_in[12];
    const float* g1  = (const float*)d_in[13];
    const float* be1 = (const float*)d_in[14];
    const float* dW1 = (const float*)d_in[15];
    const float* db1 = (const float*)d_in[16];
    const float* dW2 = (const float*)d_in[17];
    const float* db2 = (const float*)d_in[18];
    const float* dW3 = (const float*)d_in[19];
    const float* db3 = (const float*)d_in[20];

    const int n = in_sizes[0] / 128;
    const int E = in_sizes[1] / 2;
    const int nbuck = (n + 127) >> 7;

    char* ws = (char*)d_ws;
    size_t off = 0;
    auto alloc = [&](size_t bytes) -> void* {
        void* p = ws + off;
        off = (off + bytes + 255) & ~(size_t)255;
        return p;
    };
    int*      gcnt  = (int*)alloc(MAXB * 4);
    int*      gbase = (int*)alloc((MAXB + 1) * 4);
    int*      gcur  = (int*)alloc(MAXB * 4);
    unsigned* bins  = (unsigned*)alloc((size_t)E * 4);
    int*      csr   = (int*)alloc((size_t)E * 4);
    int*      offs  = (int*)alloc((size_t)(n + 1) * 4);
    __half*   x_h   = (__half*)alloc((size_t)n * 128 * 2);
    __half*   agg_h = (__half*)alloc((size_t)n * 128 * 2);
    __half*   h0    = (__half*)alloc((size_t)n * 128 * 2);
    __half*   h1    = (__half*)alloc((size_t)n * 128 * 2);
    __half*   h2    = h0;  // h0 dead after layer-1 gemm
    __half*   Wcat  = (__half*)alloc(3 * 32768 * 2);
    __half*   dWcat = (__half*)alloc(3 * 16384 * 2);

    float* out0 = (float*)d_out;
    float* out1 = out0 + (size_t)n * 128;
    float* out2 = out1 + (size_t)n * 7;

    hipMemsetAsync(gcnt, 0, MAXB * 4, stream);

    const int ggrid = (n + 127) / 128;
    const int agg_grid = (n * 64 + 255) / 256;
    const int HC = (E + 4095) / 4096;
    const int CX = (n * 16 + 255) / 256;
    const int CW = (147456 + 255) / 256;

    prep_k<<<HC + CX + CW, 256, 0, stream>>>(eb, gcnt, E, nbuck, x, x_h, n * 16,
                                             Wl0, Wr0, Wl1, Wr1, Wl2, Wr2, dW1,
                                             dW3, dW2, Wcat, dWcat, HC, CX);
    scanB_k<<<1, 512, 0, stream>>>(gcnt, gbase, gcur, offs, E, n, nbuck);
    binC_k<<<HC, 256, 0, stream>>>(eb, gcur, bins, E, nbuck);
    csrD_k<<<nbuck, 256, 0, stream>>>(bins, gbase, offs, csr, n);

    // layer 0
    agg_k<<<agg_grid, 256, 0, stream>>>(x_h, offs, csr, agg_h, n);
    mgemm_k<256, true, true, true, false><<<ggrid, 256, 0, stream>>>(
        agg_h, x_h, Wcat, b0, g0, be0, h0, nullptr, nullptr, nullptr, nullptr, n);
    // layer 1
    agg_k<<<agg_grid, 256, 0, stream>>>(h0, offs, csr, agg_h, n);
    mgemm_k<256, true, true, true, false><<<ggrid, 256, 0, stream>>>(
        agg_h, h0, Wcat + 32768, b1, g1, be1, h1, nullptr, nullptr, nullptr,
        nullptr, n);
    // layer 2 (no bn/relu); h2 aliases h0
    agg_k<<<agg_grid, 256, 0, stream>>>(h1, offs, csr, agg_h, n);
    mgemm_k<256, true, false, true, false><<<ggrid, 256, 0, stream>>>(
        agg_h, h1, Wcat + 65536, b2, nullptr, nullptr, h2, nullptr, nullptr,
        nullptr, nullptr, n);
    // fused heads: y=0 -> dW1/db1 -> out0; y=1 -> dW3/db3 -> out2;
    //              y=2 -> dW2(pad)/db2 -> out1 (7 cols)
    mgemm_k<128, false, false, false, true><<<dim3(ggrid, 3), 256, 0, stream>>>(
        h2, nullptr, dWcat, db1, nullptr, nullptr, out0, db3, out2, db2,
        out1, n);
}